// Round 4
// baseline (714.757 us; speedup 1.0000x reference)
//
#include <hip/hip_runtime.h>
#include <math.h>

// WindowAttention: B=2048, C=256, H=8, d_k=32, wh=ww=7 -> L=49, nW=64.
// Reference reassigns v = k. Outputs: score (2048*256*49) then attn
// (2048*8*49*49), fp32, concatenated in d_out.
//
// MFMA design, R4: one wave per (b,h), 4 waves per 256-thread block, each
// wave a private 8 KiB LDS quadrant (32 KiB/block -> 5 blocks/CU -> 20
// waves/CU). No barriers.
//
// R2/R3 lesson (counter-proven): frag-scattered 4B global stores rely on
// L2 write-combining with LONG line residency; above ~8 waves/CU the
// concurrent dirty-line set (waves x 16KB) exceeds the 32MB L2 and
// partially-covered lines are evicted -> partial writeback + merge-fetch
// (WRITE 256->831 MB, FETCH 182->417 MB). Fix = single-touch contiguous
// stores: every output line fully covered by 1-2 back-to-back store
// instructions, independent of occupancy (what the pre-MFMA baseline did).
//
//  phase1: S = Q^T K via mfma_f32_16x16x32_bf16 (M=N=49->64, K=32 exact),
//          RNE hi/lo bf16 split, 3 passes -> ~fp32 accuracy.
//  softmax on C-frag layout (col=lane&15, row=(lane>>4)*4+reg) via shfl_xor.
//  phase3: score = K P^T, chunked over t: stage 32 full P-rows (64 packed
//          bf16 hi|lo words, XOR-swizzled) = 8 KiB; contraction runs both
//          s-halves from in-register K2 frags. After each chunk's pack,
//          attn rows are reconstructed (hi+lo, err ~2^-17) and written as a
//          flat contiguous dword stream. Score staged f32 (stride 50) and
//          written contiguous likewise.

#define LW 49
#define NH 8

typedef short s16x8 __attribute__((ext_vector_type(8)));
typedef float f32x4 __attribute__((ext_vector_type(4)));

union Frag { s16x8 v; unsigned short u[8]; };

__device__ __forceinline__ unsigned short f2bf(float x) {
    unsigned u = __float_as_uint(x);
    u += 0x7FFFu + ((u >> 16) & 1u);          // round-to-nearest-even
    return (unsigned short)(u >> 16);
}
__device__ __forceinline__ float bf2f(unsigned short h) {
    return __uint_as_float(((unsigned)h) << 16);
}
// RNE split: hi = bf16_rne(x); lo = bf16_rne(x - hi).
__device__ __forceinline__ void split8(const float* xf, Frag& hi, Frag& lo) {
    #pragma unroll
    for (int j = 0; j < 8; j++) {
        const unsigned short hb = f2bf(xf[j]);
        hi.u[j] = hb;
        lo.u[j] = f2bf(xf[j] - bf2f(hb));
    }
}

#define MFMA16(A, B, C) __builtin_amdgcn_mfma_f32_16x16x32_bf16((A), (B), (C), 0, 0, 0)

// ---------------- prep: bias & mask expanded into C-fragment order ----------
__global__ __launch_bounds__(256) void prep_frag_kernel(
    const float* __restrict__ mask, const float* __restrict__ table,
    const int* __restrict__ idx,
    float* __restrict__ biasF, float* __restrict__ maskF)
{
    const int i = blockIdx.x * 256 + threadIdx.x;
    const int NBF = 8 * 4096;        // 32768
    const int NMF = 64 * 4096;       // 262144
    if (i < NBF) {
        const int h = i >> 12, rem = i & 4095;
        const int gi = rem >> 8, lane = (rem >> 2) & 63, r = rem & 3;
        const int mt = gi >> 2, nt = gi & 3;
        const int t = mt * 16 + (lane >> 4) * 4 + r;
        const int s = nt * 16 + (lane & 15);
        biasF[i] = (t < LW && s < LW) ? table[idx[t * LW + s] * NH + h] : 0.f;
    } else if (i < NBF + NMF) {
        const int j = i - NBF;
        const int w2 = j >> 12, rem = j & 4095;
        const int gi = rem >> 8, lane = (rem >> 2) & 63, r = rem & 3;
        const int mt = gi >> 2, nt = gi & 3;
        const int t = mt * 16 + (lane >> 4) * 4 + r;
        const int s = nt * 16 + (lane & 15);
        maskF[j] = (t < LW && s < LW) ? mask[w2 * (LW * LW) + t * LW + s] : 0.f;
    }
}

// ---------------- main: 4 waves/block, one (b,h) per wave -------------------
__global__ __launch_bounds__(256, 5) void wa_mfma_kernel(
    const float* __restrict__ q, const float* __restrict__ k,
    const float* __restrict__ biasF, const float* __restrict__ maskF,
    float* __restrict__ score_out, float* __restrict__ attn_out)
{
    __shared__ unsigned sP[4][32 * 64];   // 4 waves x 8 KiB

    const int wv   = __builtin_amdgcn_readfirstlane((int)(threadIdx.x >> 6));
    const int bh   = blockIdx.x * 4 + wv;
    const int h    = bh & 7;
    const int w    = (bh >> 3) & 63;
    const int lane = threadIdx.x & 63;
    const int l15  = lane & 15;
    const int g4   = lane >> 4;
    unsigned* sPw  = sP[wv];

    const float* qp = q + (size_t)bh * (32 * LW);
    const float* kp = k + (size_t)bh * (32 * LW);

    // ---- A-frags: Q^T rows t, k-run over c ----
    Frag Qh[4], Ql[4];
    #pragma unroll
    for (int mt = 0; mt < 4; mt++) {
        const int t  = mt * 16 + l15;
        const int tc = t < LW ? t : (LW - 1);          // clamp pad rows
        float xf[8];
        #pragma unroll
        for (int j = 0; j < 8; j++) xf[j] = qp[(g4 * 8 + j) * LW + tc];
        split8(xf, Qh[mt], Ql[mt]);
    }

    // ---- phase 1: S = Q^T K (3-pass split bf16) ----
    f32x4 acc[4][4];
    #pragma unroll
    for (int mt = 0; mt < 4; mt++)
        #pragma unroll
        for (int nt = 0; nt < 4; nt++)
            #pragma unroll
            for (int r = 0; r < 4; r++) acc[mt][nt][r] = 0.f;

    #pragma unroll
    for (int nt = 0; nt < 4; nt++) {
        const int s  = nt * 16 + l15;
        const int sc = s < LW ? s : (LW - 1);
        float xf[8];
        #pragma unroll
        for (int j = 0; j < 8; j++) xf[j] = kp[(g4 * 8 + j) * LW + sc];
        Frag Kh, Kl;
        split8(xf, Kh, Kl);
        #pragma unroll
        for (int mt = 0; mt < 4; mt++) {
            acc[mt][nt] = MFMA16(Qh[mt].v, Kh.v, acc[mt][nt]);
            acc[mt][nt] = MFMA16(Ql[mt].v, Kh.v, acc[mt][nt]);
            acc[mt][nt] = MFMA16(Qh[mt].v, Kl.v, acc[mt][nt]);
        }
    }

    // ---- A-frags for phase 3 (K rows c, k-run over s), issued early ----
    Frag K2h[2][2], K2l[2][2];
    #pragma unroll
    for (int mt = 0; mt < 2; mt++) {
        const int c = mt * 16 + l15;                   // c < 32 always
        #pragma unroll
        for (int ks = 0; ks < 2; ks++) {
            float xf[8];
            #pragma unroll
            for (int j = 0; j < 8; j++) {
                const int s  = ks * 32 + g4 * 8 + j;
                const int sc = s < LW ? s : (LW - 1);  // P at pad s is 0
                xf[j] = kp[c * LW + sc];
            }
            split8(xf, K2h[mt][ks], K2l[mt][ks]);
        }
    }

    // ---- scale + bias + mask (frag-ordered tables); pad cols -> -inf ----
    const float scale = 0.17677669529663687f;          // 32^-0.5
    const float* bF = biasF + (size_t)h * 4096 + lane * 4;
    const float* mF = maskF + (size_t)w * 4096 + lane * 4;
    #pragma unroll
    for (int mt = 0; mt < 4; mt++) {
        #pragma unroll
        for (int nt = 0; nt < 4; nt++) {
            const int gi = mt * 4 + nt;
            const f32x4 bq = *(const f32x4*)(bF + gi * 256);
            const f32x4 mq = *(const f32x4*)(mF + gi * 256);
            const bool pad = (nt * 16 + l15) >= LW;
            #pragma unroll
            for (int r = 0; r < 4; r++) {
                const float v2 = fmaf(acc[mt][nt][r], scale, bq[r] + mq[r]);
                acc[mt][nt][r] = pad ? -1e30f : v2;
            }
        }
    }

    // ---- softmax over s: row on 16 lanes (same g4 group) x 4 nt ----
    #pragma unroll
    for (int mt = 0; mt < 4; mt++) {
        #pragma unroll
        for (int r = 0; r < 4; r++) {
            float mx = fmaxf(fmaxf(acc[mt][0][r], acc[mt][1][r]),
                             fmaxf(acc[mt][2][r], acc[mt][3][r]));
            mx = fmaxf(mx, __shfl_xor(mx, 1));
            mx = fmaxf(mx, __shfl_xor(mx, 2));
            mx = fmaxf(mx, __shfl_xor(mx, 4));
            mx = fmaxf(mx, __shfl_xor(mx, 8));
            float sm = 0.f;
            #pragma unroll
            for (int nt = 0; nt < 4; nt++) {
                const float p = __expf(acc[mt][nt][r] - mx);
                acc[mt][nt][r] = p;
                sm += p;
            }
            sm += __shfl_xor(sm, 1);
            sm += __shfl_xor(sm, 2);
            sm += __shfl_xor(sm, 4);
            sm += __shfl_xor(sm, 8);
            const float inv = 1.0f / sm;
            #pragma unroll
            for (int nt = 0; nt < 4; nt++) acc[mt][nt][r] *= inv;
        }
    }

    // ---- phase 3 + attn writeout, chunked over t (32 rows = 8 KiB) ----
    float* attn_base = attn_out + (size_t)bh * (LW * LW);
    f32x4 acc2[2][4];
    #pragma unroll
    for (int mt = 0; mt < 2; mt++)
        #pragma unroll
        for (int nt = 0; nt < 4; nt++)
            #pragma unroll
            for (int r = 0; r < 4; r++) acc2[mt][nt][r] = 0.f;

    #pragma unroll
    for (int tc2 = 0; tc2 < 2; tc2++) {
        // pack P rows [tc2*32, tc2*32+32) as bf16 hi|lo, XOR-swizzled.
        // Single wave + in-order DS pipe: program order protects the WAR
        // on buffer reuse across chunks (same assumption as R2/R3, passed).
        #pragma unroll
        for (int mi = 0; mi < 2; mi++) {
            const int mt = tc2 * 2 + mi;
            #pragma unroll
            for (int r = 0; r < 4; r++) {
                const int t  = mt * 16 + g4 * 4 + r;
                const int lt = t - tc2 * 32;
                const unsigned sw = ((unsigned)t & 7u) << 2;
                #pragma unroll
                for (int nt = 0; nt < 4; nt++) {
                    const float p = acc[mt][nt][r];
                    const unsigned short ph = f2bf(p);
                    const unsigned short pl = f2bf(p - bf2f(ph));
                    const unsigned w32 = (unsigned)ph | ((unsigned)pl << 16);
                    const unsigned sl = (unsigned)(nt * 16 + l15);
                    sPw[(unsigned)lt * 64u + (sl ^ sw)] = w32;
                }
            }
        }
        // MFMAs for output cols t in this chunk (full s contraction)
        #pragma unroll
        for (int ni = 0; ni < 2; ni++) {
            const int ntt = tc2 * 2 + ni;
            const int lt  = (ntt - tc2 * 2) * 16 + l15;
            const int t   = ntt * 16 + l15;
            const unsigned sw = ((unsigned)t & 7u) << 2;
            #pragma unroll
            for (int ks = 0; ks < 2; ks++) {
                const unsigned baseA = (unsigned)lt * 64u + (unsigned)ks * 32u
                                     + (((unsigned)g4 * 8u) ^ sw);
                const uint4 a0 = *(const uint4*)&sPw[baseA];
                const uint4 a1 = *(const uint4*)&sPw[baseA ^ 4u];
                const unsigned pk[8] = {a0.x, a0.y, a0.z, a0.w,
                                        a1.x, a1.y, a1.z, a1.w};
                Frag Ph, Pl;
                #pragma unroll
                for (int e = 0; e < 8; e++) {
                    Ph.u[e] = (unsigned short)(pk[e] & 0xFFFFu);
                    Pl.u[e] = (unsigned short)(pk[e] >> 16);
                }
                #pragma unroll
                for (int mt = 0; mt < 2; mt++) {
                    acc2[mt][ntt] = MFMA16(K2h[mt][ks].v, Ph.v, acc2[mt][ntt]);
                    acc2[mt][ntt] = MFMA16(K2l[mt][ks].v, Ph.v, acc2[mt][ntt]);
                    acc2[mt][ntt] = MFMA16(K2h[mt][ks].v, Pl.v, acc2[mt][ntt]);
                }
            }
        }
        // attn writeout for this chunk: flat contiguous dword stream.
        // value = hi + lo reconstruct (error ~2^-17, far below tolerance).
        const int nEl  = (tc2 == 0) ? 32 * LW : 17 * LW;   // 1568 / 833
        const int gOff = tc2 * 32 * LW;
        for (int it = 0; it * 64 < nEl; it++) {
            const int i = it * 64 + lane;
            if (i < nEl) {
                const int lt = i / LW;
                const int s  = i - lt * LW;
                const unsigned sw2 = ((unsigned)lt & 7u) << 2;  // (t&7)==(lt&7)
                const unsigned w32 = sPw[(unsigned)lt * 64u + ((unsigned)s ^ sw2)];
                const float val = __uint_as_float(w32 << 16)
                                + __uint_as_float(w32 & 0xFFFF0000u);
                attn_base[gOff + i] = val;
            }
        }
    }

    // ---- score: stage f32 (stride 50) then flat contiguous writeout ----
    float* sPf = (float*)sPw;
    #pragma unroll
    for (int mt = 0; mt < 2; mt++) {
        #pragma unroll
        for (int nt = 0; nt < 4; nt++) {
            const int t = nt * 16 + l15;
            if (t < LW) {
                #pragma unroll
                for (int r = 0; r < 4; r++) {
                    const int c = mt * 16 + g4 * 4 + r;
                    sPf[c * 50 + t] = acc2[mt][nt][r];
                }
            }
        }
    }
    float* sc = score_out + (size_t)bh * (32 * LW);
    for (int it = 0; it < 25; it++) {
        const int i = it * 64 + lane;
        if (i < 32 * LW) {
            const int c = i / LW;
            const int t = i - c * LW;
            sc[i] = sPf[c * 50 + t];
        }
    }
}

// ---------------- fallback (ws too small): VALU kernel ----------------------
__global__ __launch_bounds__(256, 4) void wa_fallback_kernel(
    const float* __restrict__ q, const float* __restrict__ k,
    const float* __restrict__ mask0, const float* __restrict__ table,
    const int* __restrict__ idx,
    float* __restrict__ score_out, float* __restrict__ attn_out)
{
    __shared__ float sPf[LW * LW];
    const int lane = threadIdx.x & 63;
    const int wv   = __builtin_amdgcn_readfirstlane((int)(threadIdx.x >> 6));
    const int bh   = blockIdx.x * 4 + wv;
    const int h    = bh & 7;
    const int w    = (bh >> 3) & 63;
    const int t    = lane;
    const int tc   = (t < LW) ? t : (LW - 1);

    const float* qp = q + (size_t)bh * (32 * LW);
    const float* kp = k + (size_t)bh * (32 * LW);

    float qreg[32];
    #pragma unroll
    for (int c = 0; c < 32; c++) qreg[c] = qp[c * LW + tc];

    float S[LW];
    #pragma unroll
    for (int s = 0; s < LW; s++) S[s] = 0.f;
    #pragma unroll
    for (int c = 0; c < 32; c++) {
        #pragma unroll
        for (int s = 0; s < LW; s++)
            S[s] = fmaf(qreg[c], kp[c * LW + s], S[s]);
    }

    const float scale = 0.17677669529663687f;
    const float* mrow = mask0 + (size_t)w * (LW * LW) + tc * LW;
    const int*   irow = idx + tc * LW;
    #pragma unroll
    for (int s = 0; s < LW; s++) {
        const float bm = table[irow[s] * NH + h] + mrow[s];
        S[s] = fmaf(S[s], scale, bm);
    }

    float m = S[0];
    #pragma unroll
    for (int s = 1; s < LW; s++) m = fmaxf(m, S[s]);
    float sum = 0.f;
    #pragma unroll
    for (int s = 0; s < LW; s++) { S[s] = __expf(S[s] - m); sum += S[s]; }
    const float invs = 1.0f / sum;
    #pragma unroll
    for (int s = 0; s < LW; s++) S[s] *= invs;

    float* attn_base = attn_out + (size_t)bh * (LW * LW);
    for (int turn = 0; turn < 4; turn++) {
        __syncthreads();
        if (turn == wv) {
            if (t < LW) {
                #pragma unroll
                for (int s = 0; s < LW; s++) sPf[t * LW + s] = S[s];
            }
            #pragma unroll
            for (int it = 0; it < 38; it++) {
                const int i = it * 64 + lane;
                if (i < LW * LW) attn_base[i] = sPf[i];
            }
        }
    }

    float* sc = score_out + (size_t)bh * (32 * LW);
    #pragma unroll
    for (int c = 0; c < 32; c++) {
        float a = 0.f;
        #pragma unroll
        for (int s = 0; s < LW; s++) a = fmaf(S[s], kp[c * LW + s], a);
        if (t < LW) sc[c * LW + t] = a;
    }
}

extern "C" void kernel_launch(void* const* d_in, const int* in_sizes, int n_in,
                              void* d_out, int out_size, void* d_ws, size_t ws_size,
                              hipStream_t stream) {
    const float* q     = (const float*)d_in[0];
    const float* k     = (const float*)d_in[1];
    // d_in[2] = v, unused: reference reassigns v = k
    const float* mask  = (const float*)d_in[3];
    const float* table = (const float*)d_in[4];
    const int*   idx   = (const int*)d_in[5];

    float* score_out = (float*)d_out;
    float* attn_out  = score_out + (size_t)2048 * 256 * 49;

    const size_t NBF = (size_t)8 * 4096;     // 32768 floats
    const size_t NMF = (size_t)64 * 4096;    // 262144 floats

    if (ws_size >= (NBF + NMF) * sizeof(float)) {
        float* biasF = (float*)d_ws;
        float* maskF = biasF + NBF;
        const int tot = (int)(NBF + NMF);
        prep_frag_kernel<<<(tot + 255) / 256, 256, 0, stream>>>(
            mask, table, idx, biasF, maskF);
        wa_mfma_kernel<<<4096, 256, 0, stream>>>(
            q, k, biasF, maskF, score_out, attn_out);
    } else {
        wa_fallback_kernel<<<4096, 256, 0, stream>>>(
            q, k, mask, table, idx, score_out, attn_out);
    }
}

// Round 5
// 494.308 us; speedup vs baseline: 1.4460x; 1.4460x over previous
//
#include <hip/hip_runtime.h>
#include <math.h>

// WindowAttention: B=2048, C=256, H=8, d_k=32, wh=ww=7 -> L=49, nW=64.
// Reference reassigns v = k. Outputs: score (2048*256*49) then attn
// (2048*8*49*49), fp32, concatenated in d_out.
//
// MFMA design, R5: one wave per (b,h), 1 wave per 64-thread block.
//
// R2-R4 lesson (counter-proven): the HBM write/fetch "amplification" was
// SCRATCH SPILL, not store patterns. Algorithmic state ~180 regs; forcing
// VGPR caps of 102-128 via launch_bounds min-waves spilled ~50KB/wave to
// scratch (HBM): WRITE 256->589->831->1017 MB tracked the cap, not the
// store layout. Fix: launch_bounds(64,3) (cap ~170) + live-range
// restructuring to ~130 peak regs:
//   - acc (64 regs) dies right after softmax by packing ALL of P into LDS
//     (49 rows x 64 words bf16 hi|lo = 12.25 KiB -> 13 blocks/CU).
//   - K2 raw floats loaded after the pack, split after attn writeout, so
//     Q-frags/acc and K2-frags/acc2 live ranges never overlap.
// Expected ~12-13 waves/CU (regs 3/SIMD, LDS 13 blocks), no spill.
//
//  phase1: S = Q^T K via mfma_f32_16x16x32_bf16 (M=N=49->64, K=32 exact),
//          RNE hi/lo bf16 split, 3 passes -> ~fp32 accuracy.
//  softmax on C-frag layout (col=lane&15, row=(lane>>4)*4+reg) via shfl_xor.
//  phase3: score = K P^T from LDS-packed P (word-XOR swizzle ^((t&7)<<2)
//          keeps b32 writes and b128 frag reads bank-uniform).
//  attn/score written as flat contiguous dword streams via LDS readback.
//  bias+mask pre-expanded into fragment order -> coalesced f32x4 loads.

#define LW 49
#define NH 8

typedef short s16x8 __attribute__((ext_vector_type(8)));
typedef float f32x4 __attribute__((ext_vector_type(4)));

union Frag { s16x8 v; unsigned short u[8]; };

__device__ __forceinline__ unsigned short f2bf(float x) {
    unsigned u = __float_as_uint(x);
    u += 0x7FFFu + ((u >> 16) & 1u);          // round-to-nearest-even
    return (unsigned short)(u >> 16);
}
__device__ __forceinline__ float bf2f(unsigned short h) {
    return __uint_as_float(((unsigned)h) << 16);
}
// RNE split: hi = bf16_rne(x); lo = bf16_rne(x - hi).
__device__ __forceinline__ void split8(const float* xf, Frag& hi, Frag& lo) {
    #pragma unroll
    for (int j = 0; j < 8; j++) {
        const unsigned short hb = f2bf(xf[j]);
        hi.u[j] = hb;
        lo.u[j] = f2bf(xf[j] - bf2f(hb));
    }
}

#define MFMA16(A, B, C) __builtin_amdgcn_mfma_f32_16x16x32_bf16((A), (B), (C), 0, 0, 0)

// ---------------- prep: bias & mask expanded into C-fragment order ----------
__global__ __launch_bounds__(256) void prep_frag_kernel(
    const float* __restrict__ mask, const float* __restrict__ table,
    const int* __restrict__ idx,
    float* __restrict__ biasF, float* __restrict__ maskF)
{
    const int i = blockIdx.x * 256 + threadIdx.x;
    const int NBF = 8 * 4096;        // 32768
    const int NMF = 64 * 4096;       // 262144
    if (i < NBF) {
        const int h = i >> 12, rem = i & 4095;
        const int gi = rem >> 8, lane = (rem >> 2) & 63, r = rem & 3;
        const int mt = gi >> 2, nt = gi & 3;
        const int t = mt * 16 + (lane >> 4) * 4 + r;
        const int s = nt * 16 + (lane & 15);
        biasF[i] = (t < LW && s < LW) ? table[idx[t * LW + s] * NH + h] : 0.f;
    } else if (i < NBF + NMF) {
        const int j = i - NBF;
        const int w2 = j >> 12, rem = j & 4095;
        const int gi = rem >> 8, lane = (rem >> 2) & 63, r = rem & 3;
        const int mt = gi >> 2, nt = gi & 3;
        const int t = mt * 16 + (lane >> 4) * 4 + r;
        const int s = nt * 16 + (lane & 15);
        maskF[j] = (t < LW && s < LW) ? mask[w2 * (LW * LW) + t * LW + s] : 0.f;
    }
}

// ---------------- main: 1 wave per (b,h) ------------------------------------
__global__ __launch_bounds__(64, 3) void wa_mfma_kernel(
    const float* __restrict__ q, const float* __restrict__ k,
    const float* __restrict__ biasF, const float* __restrict__ maskF,
    float* __restrict__ score_out, float* __restrict__ attn_out)
{
    __shared__ unsigned sP[LW * 64];      // 49 rows x 64 words = 12544 B

    const int bh   = blockIdx.x;
    const int h    = bh & 7;
    const int w    = (bh >> 3) & 63;
    const int lane = threadIdx.x;         // 0..63, single wave
    const int l15  = lane & 15;
    const int g4   = lane >> 4;

    const float* qp = q + (size_t)bh * (32 * LW);
    const float* kp = k + (size_t)bh * (32 * LW);

    // ---- A-frags: Q^T rows t, k-run over c ----
    Frag Qh[4], Ql[4];
    #pragma unroll
    for (int mt = 0; mt < 4; mt++) {
        const int t  = mt * 16 + l15;
        const int tc = t < LW ? t : (LW - 1);          // clamp pad rows
        float xf[8];
        #pragma unroll
        for (int j = 0; j < 8; j++) xf[j] = qp[(g4 * 8 + j) * LW + tc];
        split8(xf, Qh[mt], Ql[mt]);
    }

    // ---- phase 1: S = Q^T K (3-pass split bf16) ----
    f32x4 acc[4][4];
    #pragma unroll
    for (int mt = 0; mt < 4; mt++)
        #pragma unroll
        for (int nt = 0; nt < 4; nt++)
            #pragma unroll
            for (int r = 0; r < 4; r++) acc[mt][nt][r] = 0.f;

    #pragma unroll
    for (int nt = 0; nt < 4; nt++) {
        const int s  = nt * 16 + l15;
        const int sc = s < LW ? s : (LW - 1);
        float xf[8];
        #pragma unroll
        for (int j = 0; j < 8; j++) xf[j] = kp[(g4 * 8 + j) * LW + sc];
        Frag Kh, Kl;
        split8(xf, Kh, Kl);
        #pragma unroll
        for (int mt = 0; mt < 4; mt++) {
            acc[mt][nt] = MFMA16(Qh[mt].v, Kh.v, acc[mt][nt]);
            acc[mt][nt] = MFMA16(Ql[mt].v, Kh.v, acc[mt][nt]);
            acc[mt][nt] = MFMA16(Qh[mt].v, Kl.v, acc[mt][nt]);
        }
    }

    // ---- scale + bias + mask (frag-ordered tables); pad cols -> -inf ----
    const float scale = 0.17677669529663687f;          // 32^-0.5
    const float* bF = biasF + (size_t)h * 4096 + lane * 4;
    const float* mF = maskF + (size_t)w * 4096 + lane * 4;
    #pragma unroll
    for (int mt = 0; mt < 4; mt++) {
        #pragma unroll
        for (int nt = 0; nt < 4; nt++) {
            const int gi = mt * 4 + nt;
            const f32x4 bq = *(const f32x4*)(bF + gi * 256);
            const f32x4 mq = *(const f32x4*)(mF + gi * 256);
            const bool pad = (nt * 16 + l15) >= LW;
            #pragma unroll
            for (int r = 0; r < 4; r++) {
                const float v2 = fmaf(acc[mt][nt][r], scale, bq[r] + mq[r]);
                acc[mt][nt][r] = pad ? -1e30f : v2;
            }
        }
    }

    // ---- softmax over s: row on 16 lanes (same g4 group) x 4 nt ----
    #pragma unroll
    for (int mt = 0; mt < 4; mt++) {
        #pragma unroll
        for (int r = 0; r < 4; r++) {
            float mx = fmaxf(fmaxf(acc[mt][0][r], acc[mt][1][r]),
                             fmaxf(acc[mt][2][r], acc[mt][3][r]));
            mx = fmaxf(mx, __shfl_xor(mx, 1));
            mx = fmaxf(mx, __shfl_xor(mx, 2));
            mx = fmaxf(mx, __shfl_xor(mx, 4));
            mx = fmaxf(mx, __shfl_xor(mx, 8));
            float sm = 0.f;
            #pragma unroll
            for (int nt = 0; nt < 4; nt++) {
                const float p = __expf(acc[mt][nt][r] - mx);
                acc[mt][nt][r] = p;
                sm += p;
            }
            sm += __shfl_xor(sm, 1);
            sm += __shfl_xor(sm, 2);
            sm += __shfl_xor(sm, 4);
            sm += __shfl_xor(sm, 8);
            const float inv = 1.0f / sm;
            #pragma unroll
            for (int nt = 0; nt < 4; nt++) acc[mt][nt][r] *= inv;
        }
    }

    // ---- pack ALL of P into LDS (bf16 hi|lo, XOR-swizzled); acc dies ----
    // Pad cols s>=49 hold exact 0 (exp(-1e30-mx)=0) -> contribute 0 in MFMA.
    #pragma unroll
    for (int mt = 0; mt < 4; mt++) {
        #pragma unroll
        for (int r = 0; r < 4; r++) {
            const int t = mt * 16 + g4 * 4 + r;
            if (t < LW) {
                const unsigned sw = ((unsigned)t & 7u) << 2;
                #pragma unroll
                for (int nt = 0; nt < 4; nt++) {
                    const float p = acc[mt][nt][r];
                    const unsigned short ph = f2bf(p);
                    const unsigned short pl = f2bf(p - bf2f(ph));
                    const unsigned w32 = (unsigned)ph | ((unsigned)pl << 16);
                    const unsigned sl = (unsigned)(nt * 16 + l15);
                    sP[(unsigned)t * 64u + (sl ^ sw)] = w32;
                }
            }
        }
    }

    // ---- issue K2 raw loads now (latency hides under attn writeout) ----
    float k2raw[2][2][8];
    #pragma unroll
    for (int mt = 0; mt < 2; mt++) {
        const int c = mt * 16 + l15;                   // c < 32 always
        #pragma unroll
        for (int ks = 0; ks < 2; ks++) {
            #pragma unroll
            for (int j = 0; j < 8; j++) {
                const int s  = ks * 32 + g4 * 8 + j;
                const int sc = s < LW ? s : (LW - 1);  // P at pad s is 0
                k2raw[mt][ks][j] = kp[c * LW + sc];
            }
        }
    }

    // ---- attn writeout: flat contiguous dword stream (hi+lo reconstruct,
    //      err ~2^-17). Single wave: in-order DS orders pack -> readback ----
    float* attn_base = attn_out + (size_t)bh * (LW * LW);
    for (int it = 0; it < 38; it++) {
        const int i = it * 64 + lane;
        if (i < LW * LW) {
            const int lt = i / LW;
            const int s  = i - lt * LW;
            const unsigned sw2 = ((unsigned)lt & 7u) << 2;
            const unsigned w32 = sP[(unsigned)lt * 64u + ((unsigned)s ^ sw2)];
            attn_base[i] = __uint_as_float(w32 << 16)
                         + __uint_as_float(w32 & 0xFFFF0000u);
        }
    }

    // ---- split K2 into frags ----
    Frag K2h[2][2], K2l[2][2];
    #pragma unroll
    for (int mt = 0; mt < 2; mt++)
        #pragma unroll
        for (int ks = 0; ks < 2; ks++)
            split8(k2raw[mt][ks], K2h[mt][ks], K2l[mt][ks]);

    // ---- phase 3: score(c,t) = sum_s K(c,s) P(t,s) from LDS P ----
    f32x4 acc2[2][4];
    #pragma unroll
    for (int mt = 0; mt < 2; mt++)
        #pragma unroll
        for (int nt = 0; nt < 4; nt++)
            #pragma unroll
            for (int r = 0; r < 4; r++) acc2[mt][nt][r] = 0.f;

    #pragma unroll
    for (int ntt = 0; ntt < 4; ntt++) {
        const int t  = ntt * 16 + l15;
        const int tr = t < LW ? t : (LW - 1);          // clamped rows: lanes
        const unsigned sw = ((unsigned)tr & 7u) << 2;  // discarded at store
        #pragma unroll
        for (int ks = 0; ks < 2; ks++) {
            const unsigned baseA = (unsigned)tr * 64u + (unsigned)ks * 32u
                                 + (((unsigned)g4 * 8u) ^ sw);
            const uint4 a0 = *(const uint4*)&sP[baseA];
            const uint4 a1 = *(const uint4*)&sP[baseA ^ 4u];
            const unsigned pk[8] = {a0.x, a0.y, a0.z, a0.w,
                                    a1.x, a1.y, a1.z, a1.w};
            Frag Ph, Pl;
            #pragma unroll
            for (int e = 0; e < 8; e++) {
                Ph.u[e] = (unsigned short)(pk[e] & 0xFFFFu);
                Pl.u[e] = (unsigned short)(pk[e] >> 16);
            }
            #pragma unroll
            for (int mt = 0; mt < 2; mt++) {
                acc2[mt][ntt] = MFMA16(K2h[mt][ks].v, Ph.v, acc2[mt][ntt]);
                acc2[mt][ntt] = MFMA16(K2l[mt][ks].v, Ph.v, acc2[mt][ntt]);
                acc2[mt][ntt] = MFMA16(K2h[mt][ks].v, Pl.v, acc2[mt][ntt]);
            }
        }
    }

    // ---- score: stage f32 (stride 50, reuse sP) then contiguous writeout ----
    float* sPf = (float*)sP;
    #pragma unroll
    for (int mt = 0; mt < 2; mt++) {
        #pragma unroll
        for (int nt = 0; nt < 4; nt++) {
            const int t = nt * 16 + l15;
            if (t < LW) {
                #pragma unroll
                for (int r = 0; r < 4; r++) {
                    const int c = mt * 16 + g4 * 4 + r;
                    sPf[c * 50 + t] = acc2[mt][nt][r];
                }
            }
        }
    }
    float* sc = score_out + (size_t)bh * (32 * LW);
    for (int it = 0; it < 25; it++) {
        const int i = it * 64 + lane;
        if (i < 32 * LW) {
            const int c = i / LW;
            const int t = i - c * LW;
            sc[i] = sPf[c * 50 + t];
        }
    }
}

// ---------------- fallback (ws too small): VALU kernel ----------------------
__global__ __launch_bounds__(256, 4) void wa_fallback_kernel(
    const float* __restrict__ q, const float* __restrict__ k,
    const float* __restrict__ mask0, const float* __restrict__ table,
    const int* __restrict__ idx,
    float* __restrict__ score_out, float* __restrict__ attn_out)
{
    __shared__ float sPf[LW * LW];
    const int lane = threadIdx.x & 63;
    const int wv   = __builtin_amdgcn_readfirstlane((int)(threadIdx.x >> 6));
    const int bh   = blockIdx.x * 4 + wv;
    const int h    = bh & 7;
    const int w    = (bh >> 3) & 63;
    const int t    = lane;
    const int tc   = (t < LW) ? t : (LW - 1);

    const float* qp = q + (size_t)bh * (32 * LW);
    const float* kp = k + (size_t)bh * (32 * LW);

    float qreg[32];
    #pragma unroll
    for (int c = 0; c < 32; c++) qreg[c] = qp[c * LW + tc];

    float S[LW];
    #pragma unroll
    for (int s = 0; s < LW; s++) S[s] = 0.f;
    #pragma unroll
    for (int c = 0; c < 32; c++) {
        #pragma unroll
        for (int s = 0; s < LW; s++)
            S[s] = fmaf(qreg[c], kp[c * LW + s], S[s]);
    }

    const float scale = 0.17677669529663687f;
    const float* mrow = mask0 + (size_t)w * (LW * LW) + tc * LW;
    const int*   irow = idx + tc * LW;
    #pragma unroll
    for (int s = 0; s < LW; s++) {
        const float bm = table[irow[s] * NH + h] + mrow[s];
        S[s] = fmaf(S[s], scale, bm);
    }

    float m = S[0];
    #pragma unroll
    for (int s = 1; s < LW; s++) m = fmaxf(m, S[s]);
    float sum = 0.f;
    #pragma unroll
    for (int s = 0; s < LW; s++) { S[s] = __expf(S[s] - m); sum += S[s]; }
    const float invs = 1.0f / sum;
    #pragma unroll
    for (int s = 0; s < LW; s++) S[s] *= invs;

    float* attn_base = attn_out + (size_t)bh * (LW * LW);
    for (int turn = 0; turn < 4; turn++) {
        __syncthreads();
        if (turn == wv) {
            if (t < LW) {
                #pragma unroll
                for (int s = 0; s < LW; s++) sPf[t * LW + s] = S[s];
            }
            #pragma unroll
            for (int it = 0; it < 38; it++) {
                const int i = it * 64 + lane;
                if (i < LW * LW) attn_base[i] = sPf[i];
            }
        }
    }

    float* sc = score_out + (size_t)bh * (32 * LW);
    #pragma unroll
    for (int c = 0; c < 32; c++) {
        float a = 0.f;
        #pragma unroll
        for (int s = 0; s < LW; s++) a = fmaf(S[s], kp[c * LW + s], a);
        if (t < LW) sc[c * LW + t] = a;
    }
}

extern "C" void kernel_launch(void* const* d_in, const int* in_sizes, int n_in,
                              void* d_out, int out_size, void* d_ws, size_t ws_size,
                              hipStream_t stream) {
    const float* q     = (const float*)d_in[0];
    const float* k     = (const float*)d_in[1];
    // d_in[2] = v, unused: reference reassigns v = k
    const float* mask  = (const float*)d_in[3];
    const float* table = (const float*)d_in[4];
    const int*   idx   = (const int*)d_in[5];

    float* score_out = (float*)d_out;
    float* attn_out  = score_out + (size_t)2048 * 256 * 49;

    const size_t NBF = (size_t)8 * 4096;     // 32768 floats
    const size_t NMF = (size_t)64 * 4096;    // 262144 floats

    if (ws_size >= (NBF + NMF) * sizeof(float)) {
        float* biasF = (float*)d_ws;
        float* maskF = biasF + NBF;
        const int tot = (int)(NBF + NMF);
        prep_frag_kernel<<<(tot + 255) / 256, 256, 0, stream>>>(
            mask, table, idx, biasF, maskF);
        wa_mfma_kernel<<<16384, 64, 0, stream>>>(
            q, k, biasF, maskF, score_out, attn_out);
    } else {
        wa_fallback_kernel<<<4096, 256, 0, stream>>>(
            q, k, mask, table, idx, score_out, attn_out);
    }
}